// Round 3
// baseline (567.337 us; speedup 1.0000x reference)
//
#include <hip/hip_runtime.h>
#include <math.h>

typedef __attribute__((ext_vector_type(8))) short short8;
typedef __attribute__((ext_vector_type(4))) float floatx4;

// fp32 -> bf16, round-to-nearest-even, bit pattern in a short
__device__ __forceinline__ short f2bf(float f) {
  union { float f; unsigned u; } v; v.f = f;
  unsigned r = v.u + 0x7fffu + ((v.u >> 16) & 1u);
  return (short)(r >> 16);
}

struct GParams {
  const float* fs[5];
  const float* ft[5];
  const float* bias[5];
  const float* mask[5];
  const short8* wp[5];
  float* sums;   // [0..9] level sums, [12] completion counter (as uint)
  float* out;
};

// ---------------------------------------------------------------------------
// prep_all: one launch doing W-prepack (blocks 0..159), mask raster
// (blocks 160..199), and sums/counter zeroing (block 200).
// wp fragment order: flat short8 idx = (t16*8+kt)*64+lane holding
// W[t16*16+(lane&15)][kt*32+(lane>>4)*8 .. +7] as bf16.
// ---------------------------------------------------------------------------
__global__ void prep_all(const float* __restrict__ w0, const float* __restrict__ w1,
                         const float* __restrict__ w2, const float* __restrict__ w3,
                         const float* __restrict__ w4, const float* __restrict__ gtb,
                         float* __restrict__ mask_base, short8* __restrict__ wp,
                         float* __restrict__ sums) {
  int bid = blockIdx.x;
  if (bid == 200) {
    if (threadIdx.x < 16) sums[threadIdx.x] = 0.f;
    return;
  }
  if (bid < 160) {
    int id = bid * 256 + threadIdx.x;
    int lvl = id >> 13;
    int idx = id & 8191;
    const float* W = (lvl == 0) ? w0 : (lvl == 1) ? w1 : (lvl == 2) ? w2 : (lvl == 3) ? w3 : w4;
    int t16 = idx >> 9;
    int kt  = (idx >> 6) & 7;
    int ln  = idx & 63;
    int m = t16 * 16 + (ln & 15);
    int c = kt * 32 + (ln >> 4) * 8;
    const float* s = W + m * 256 + c;
    short8 v;
#pragma unroll
    for (int j = 0; j < 8; j++) v[j] = f2bf(s[j]);
    wp[id] = v;
    return;
  }
  // mask raster
  const int szs[5]  = {128, 64, 32, 16, 8};
  const int strd[5] = {8, 16, 32, 64, 128};
  const int offs[5] = {0, 131072, 163840, 172032, 174080};
  int id = bid - 160;
  int b = id & 7, lvl = id >> 3;
  int hw = szs[lvl];
  int P = hw * hw;
  __shared__ int lx[16], ly[16], rx[16], ry[16], dg[16];
  if (threadIdx.x < 16) {
    int n = threadIdx.x;
    const float* bb = gtb + (b * 16 + n) * 4;
    float inv = 1.0f / (float)strd[lvl];   // pow2 stride -> exact
    int qx1 = (int)floorf(bb[0] * inv);
    int qy1 = (int)floorf(bb[1] * inv);
    int qx2 = (int)floorf(bb[2] * inv);
    int qy2 = (int)floorf(bb[3] * inv);
    int wl = hw - 1;
    int a = min(qx1, wl), c = min(qy1, wl), d = min(qx2, wl), e = min(qy2, wl);
    lx[n] = a; ly[n] = c; rx[n] = d; ry[n] = e;
    dg[n] = (a == d) || (c == e);
  }
  __syncthreads();
  float* mp = mask_base + offs[lvl] + b * P;
  for (int p = threadIdx.x; p < P; p += blockDim.x) {
    int y = p / hw, x = p - y * hw;
    bool any = false;
#pragma unroll
    for (int n = 0; n < 16; n++) {
      bool cov = dg[n] ? (y == ly[n] && x == lx[n])
                       : (y >= ly[n] && y < ry[n] && x >= lx[n] && x < rx[n]);
      any = any || cov;
    }
    mp[p] = any ? 1.0f : 0.0f;
  }
}

// ---------------------------------------------------------------------------
// Fused GEMM + masked loss. Block = 4 waves, tile 256(o) x 64(p), K=256.
// The block's ENTIRE fs panel (256K x 64p = 64 KB fp32) is register-staged:
// 16 contiguous dwordx4 loads per thread issued up-front (16 KB/wave in
// flight -> BW-optimal even if the first barrier drains vmcnt). Transpose to
// MFMA B-layout goes through a double-buffered 8 KB LDS tile with an XOR
// swizzle making fragment reads exactly 2-way bank-aliased (free per m136).
// Last block (device atomic counter) computes the final scalar -> no
// separate finalize launch.
// ---------------------------------------------------------------------------
template<int PL2, int LVL>
__device__ __forceinline__ void level_body(const GParams& pr, int rem, float* lds) {
  constexpr int P = 64 << PL2;
  const int tid  = threadIdx.x;
  const int lane = tid & 63;
  const int wave = tid >> 6;
  const int quad = lane >> 4, l15 = lane & 15;
  const int bz = rem >> PL2;
  const int p0 = (rem & ((1 << PL2) - 1)) << 6;

  const float*  fsb   = pr.fs[LVL] + (size_t)bz * 256 * P + p0;
  const float*  ftb   = pr.ft[LVL] + (size_t)bz * 256 * P;
  const short8* wpb   = pr.wp[LVL] + wave * 4 * 8 * 64;   // t16 = wave*4+mi
  const float*  maskb = pr.mask[LVL] + (size_t)bz * P;
  const float*  biasp = pr.bias[LVL];

  float* buf0 = lds;
  float* buf1 = lds + 2048;
  float* red  = lds + 4096;

  // ---- register-stage the whole fs panel: 16 x float4 per thread ----
  const int fA = tid * 2,  cA = fA >> 4, pA = (fA & 15) << 2;
  const int fB = fA + 1,   cB = fB >> 4, pB = (fB & 15) << 2;
  floatx4 fr[16];
#pragma unroll
  for (int kt = 0; kt < 8; kt++) {
    fr[kt * 2]     = *(const floatx4*)(fsb + (size_t)(kt * 32 + cA) * P + pA);
    fr[kt * 2 + 1] = *(const floatx4*)(fsb + (size_t)(kt * 32 + cB) * P + pB);
  }
  const int swA = cA * 64 + (pA ^ ((cA >> 3) << 4));
  const int swB = cB * 64 + (pB ^ ((cB >> 3) << 4));

  floatx4 acc[4][4];
#pragma unroll
  for (int i = 0; i < 4; i++)
#pragma unroll
    for (int j = 0; j < 4; j++) acc[i][j] = (floatx4){0.f, 0.f, 0.f, 0.f};

  *(floatx4*)(buf0 + swA) = fr[0];
  *(floatx4*)(buf0 + swB) = fr[1];
  __syncthreads();

#pragma unroll
  for (int kt = 0; kt < 8; kt++) {
    float* rb = (kt & 1) ? buf1 : buf0;
    float* wb = (kt & 1) ? buf0 : buf1;
    if (kt < 7) {   // prefetch next tile into the other buffer
      *(floatx4*)(wb + swA) = fr[(kt + 1) * 2];
      *(floatx4*)(wb + swB) = fr[(kt + 1) * 2 + 1];
    }
    short8 af[4];
#pragma unroll
    for (int mi = 0; mi < 4; mi++) af[mi] = wpb[(mi * 8 + kt) * 64 + lane];

    short8 bfr[4];
#pragma unroll
    for (int ni = 0; ni < 4; ni++) {
      short8 v;
#pragma unroll
      for (int j = 0; j < 8; j++) {
        float x = rb[(quad * 8 + j) * 64 + ((ni * 16 + l15) ^ (quad << 4))];
        v[j] = f2bf(x);
      }
      bfr[ni] = v;
    }
#pragma unroll
    for (int mi = 0; mi < 4; mi++)
#pragma unroll
      for (int ni = 0; ni < 4; ni++)
        acc[mi][ni] = __builtin_amdgcn_mfma_f32_16x16x32_bf16(af[mi], bfr[ni], acc[mi][ni], 0, 0, 0);
    __syncthreads();
  }

  // ---- epilogue: diff^2 vs feat_t, masked accumulate ----
  float sgt = 0.f, sbg = 0.f;
#pragma unroll
  for (int ni = 0; ni < 4; ni++) {
    int p = p0 + ni * 16 + l15;
    float mk = maskb[p];
#pragma unroll
    for (int mi = 0; mi < 4; mi++) {
      int ob = wave * 64 + mi * 16 + quad * 4;
      const float* ftp = ftb + (size_t)ob * P + p;
#pragma unroll
      for (int r = 0; r < 4; r++) {
        float ad = acc[mi][ni][r] + biasp[ob + r];
        float tv = ftp[(size_t)r * P];
        float d = tv - ad;
        float sq = d * d;
        sgt += sq * mk;
        sbg += sq - sq * mk;
      }
    }
  }
#pragma unroll
  for (int off = 32; off > 0; off >>= 1) {
    sgt += __shfl_down(sgt, off);
    sbg += __shfl_down(sbg, off);
  }
  if (lane == 0) { red[wave * 2] = sgt; red[wave * 2 + 1] = sbg; }
  __syncthreads();
  if (tid == 0) {
    atomicAdd(&pr.sums[LVL * 2 + 0], red[0] + red[2] + red[4] + red[6]);
    atomicAdd(&pr.sums[LVL * 2 + 1], red[1] + red[3] + red[5] + red[7]);
    __threadfence();
    unsigned old = atomicAdd((unsigned int*)(pr.sums + 12), 1u);
    if (old == 2727u) {   // last block finalizes
      float L = 0.f;
#pragma unroll
      for (int i = 0; i < 5; i++) {
        float a = atomicAdd(&pr.sums[2 * i + 0], 0.f);
        float b = atomicAdd(&pr.sums[2 * i + 1], 0.f);
        L += 0.004f * sqrtf(a + 1e-8f) + 0.0002f * sqrtf(b + 1e-8f);
      }
      pr.out[0] = L;
    }
  }
}

// block-id ranges: L0 [0,2048) L1 [2048,2560) L2 [2560,2688) L3 [2688,2720) L4 [2720,2728)
__global__ __launch_bounds__(256, 2) void gemm_loss_all(GParams pr) {
  __shared__ float lds[4096 + 16];
  int id = blockIdx.x;
  if (id < 2048)      level_body<8, 0>(pr, id,        lds);
  else if (id < 2560) level_body<6, 1>(pr, id - 2048, lds);
  else if (id < 2688) level_body<4, 2>(pr, id - 2560, lds);
  else if (id < 2720) level_body<2, 3>(pr, id - 2688, lds);
  else                level_body<0, 4>(pr, id - 2720, lds);
}

extern "C" void kernel_launch(void* const* d_in, const int* in_sizes, int n_in,
                              void* d_out, int out_size, void* d_ws, size_t ws_size,
                              hipStream_t stream) {
  (void)in_sizes; (void)n_in; (void)out_size; (void)ws_size;
  const float* fs[5]; const float* ftp[5]; const float* aw[5]; const float* ab[5];
  for (int i = 0; i < 5; i++) {
    fs[i]  = (const float*)d_in[4 * i + 0];
    ftp[i] = (const float*)d_in[4 * i + 1];
    aw[i]  = (const float*)d_in[4 * i + 2];
    ab[i]  = (const float*)d_in[4 * i + 3];
  }
  const float* gtb = (const float*)d_in[20];
  float* out = (float*)d_out;
  char* ws = (char*)d_ws;

  float*  sums  = (float*)ws;                    // 16 floats (10 sums + counter@12)
  float*  masks = (float*)(ws + 64);             // 174592 floats
  short8* wp    = (short8*)(ws + 64 + 698368);   // 5 * 8192 short8, 16B aligned

  prep_all<<<201, 256, 0, stream>>>(aw[0], aw[1], aw[2], aw[3], aw[4], gtb, masks, wp, sums);

  const int moff[5] = {0, 131072, 163840, 172032, 174080};
  GParams pr;
  for (int l = 0; l < 5; l++) {
    pr.fs[l]   = fs[l];
    pr.ft[l]   = ftp[l];
    pr.bias[l] = ab[l];
    pr.mask[l] = masks + moff[l];
    pr.wp[l]   = wp + l * 8192;
  }
  pr.sums = sums;
  pr.out  = out;

  gemm_loss_all<<<2728, 256, 0, stream>>>(pr);
}